// Round 6
// baseline (573.354 us; speedup 1.0000x reference)
//
#include <hip/hip_runtime.h>

// Luong dot attention, B=8, T=S=2048, D=1024, fp32 in/out.
// Fast path (ws >= 192 MiB):
//   P1: trg -> fp16
//   P2: src -> fp16 hi + fp16 lo ([S][D]) + fp16 transposed hi ([D][S])
//   G1: scores = trg16 @ (srcHi+srcLo)^T, fp16 2-pass, 256x256 tile, BK=32,
//       triple-buffered LDS, per-phase lockstep, counted vmcnt (measured best)
//   SM: softmax fp32 in place + w16 (4 rows/block, wave-per-row)
//   G2: context = w16 @ srcT, 128x256 tile -> 512 blocks = 2 blocks/CU,
//       tri-buffer gl2lds, counted vmcnt (R1 structure, new geometry)
// Fallback = round-1 kernels.

#define BB 8
#define TT 2048
#define SS 2048
#define DD 1024

typedef float  f32x4   __attribute__((ext_vector_type(4)));
typedef float  f32x16  __attribute__((ext_vector_type(16)));
typedef short  bf16x8  __attribute__((ext_vector_type(8)));
typedef _Float16 f16x8 __attribute__((ext_vector_type(8)));
typedef _Float16 f16x4 __attribute__((ext_vector_type(4)));

static __device__ __forceinline__ unsigned short bf16_rne(float x) {
  unsigned int u = __float_as_uint(x);
  u += 0x7FFFu + ((u >> 16) & 1u);
  return (unsigned short)(u >> 16);
}

static __device__ __forceinline__ void gl2lds16(const void* g, void* l) {
  __builtin_amdgcn_global_load_lds(
      (const __attribute__((address_space(1))) unsigned int*)g,
      (__attribute__((address_space(3))) unsigned int*)l, 16, 0, 0);
}

// Bank-perfect LDS layout for an [R]x16-half region (R rows, 16 halves/row).
// Row r, half h: halves offset = (r>>2)*64 + (2*(r&3) + (h ^ ((r>>2)&1)))*8.
static __device__ __forceinline__ int ldsoff_h(int r, int h) {
  return ((r >> 2) << 6) + ((((r & 3) << 1) + (h ^ ((r >> 2) & 1))) << 3);
}

// ---------------------------------------------------------------------------
// P1: trg fp32 -> fp16 (single).
// ---------------------------------------------------------------------------
__global__ __launch_bounds__(256)
void conv_trg_f16(const float* __restrict__ x, _Float16* __restrict__ h16) {
  const size_t i = ((size_t)blockIdx.x * 256 + threadIdx.x) * 8;
  float4 v0 = *(const float4*)(x + i);
  float4 v1 = *(const float4*)(x + i + 4);
  f16x8 h;
  h[0] = (_Float16)v0.x; h[1] = (_Float16)v0.y;
  h[2] = (_Float16)v0.z; h[3] = (_Float16)v0.w;
  h[4] = (_Float16)v1.x; h[5] = (_Float16)v1.y;
  h[6] = (_Float16)v1.z; h[7] = (_Float16)v1.w;
  *(f16x8*)(h16 + i) = h;
}

// ---------------------------------------------------------------------------
// P2: src fp32 -> fp16 hi + fp16 lo ([S][D]) + fp16 transposed hi ([D][S]).
// ---------------------------------------------------------------------------
__global__ __launch_bounds__(256)
void conv_src_f16_hilo_t(const float* __restrict__ src,
                         _Float16* __restrict__ hi,
                         _Float16* __restrict__ lo,
                         _Float16* __restrict__ srcT) {
  const int b  = blockIdx.z;
  const int d0 = blockIdx.x * 64;
  const int s0 = blockIdx.y * 64;
  const float* S = src + (size_t)b * SS * DD;
  __shared__ _Float16 t16[64][65];
  const int t = threadIdx.x;

#pragma unroll
  for (int p = 0; p < 4; ++p) {
    const int r = p * 16 + (t >> 4);
    const int c = (t & 15) * 4;
    float4 v = *(const float4*)(S + (size_t)(s0 + r) * DD + d0 + c);
    float f[4] = {v.x, v.y, v.z, v.w};
    f16x4 h, l;
#pragma unroll
    for (int e = 0; e < 4; ++e) {
      _Float16 hv = (_Float16)f[e];
      h[e] = hv;
      l[e] = (_Float16)(f[e] - (float)hv);
      t16[r][c + e] = hv;
    }
    const size_t go = ((size_t)b * SS + s0 + r) * DD + d0 + c;
    *(f16x4*)(hi + go) = h;
    *(f16x4*)(lo + go) = l;
  }
  __syncthreads();
#pragma unroll
  for (int p = 0; p < 4; ++p) {
    const int d  = p * 16 + (t >> 4);
    const int sq = (t & 15) * 4;
    f16x4 o;
#pragma unroll
    for (int k = 0; k < 4; ++k) o[k] = t16[sq + k][d];
    *(f16x4*)(srcT + ((size_t)b * DD + d0 + d) * SS + s0 + sq) = o;
  }
}

// ---------------------------------------------------------------------------
// G1: scores = trg16 @ src16^T, fp16 2-pass (A single, B hi+lo).
// 256x256 tile, BK=32, 8 waves (2Mx4N, per-wave 128x64), 32x32x16 MFMA.
// Triple-buffered LDS, 2 lockstep phases per K-tile, counted vmcnt.
// (measured best: ~146 us)
// ---------------------------------------------------------------------------
__global__ __launch_bounds__(512, 2)
void attn_gemm1_pipe(const _Float16* __restrict__ a16,
                     const _Float16* __restrict__ bh16,
                     const _Float16* __restrict__ bl16,
                     float* __restrict__ scores) {
  const int b   = blockIdx.z;
  const int tm0 = blockIdx.y * 256;
  const int tn0 = blockIdx.x * 256;
  float* C = scores + (size_t)b * TT * SS;

  __shared__ __align__(16) _Float16 sm[3][24576];   // 144 KB

  const int t      = threadIdx.x;            // 0..511
  const int lane   = t & 63;
  const int wv     = t >> 6;                 // 0..7
  const int wm     = (wv >> 2) * 128;        // 0 / 128
  const int wn     = (wv & 3) * 64;          // 0..192
  const int lrow32 = lane & 31;
  const int khalf  = lane >> 5;

  // staging: 3072 16B-chunks per buffer; thread t covers chunks j*512+t.
  const _Float16* gp[6];
  {
    const _Float16* base0 = a16  + ((size_t)b * TT + tm0) * DD;
    const _Float16* base1 = bh16 + ((size_t)b * SS + tn0) * DD;
    const _Float16* base2 = bl16 + ((size_t)b * SS + tn0) * DD;
    const _Float16* bases[3] = {base0, base1, base2};
#pragma unroll
    for (int j = 0; j < 6; ++j) {
      const int kk   = j & 1;
      const int cc   = t;
      const int line = cc >> 3, slot = cc & 7;
      const int r    = (line << 2) + (slot >> 1);
      const int h    = (slot & 1) ^ (line & 1);
      gp[j] = bases[j >> 1] + (size_t)r * DD + kk * 16 + h * 8;
    }
  }
#define STG1(buf, j) do { gl2lds16(gp[j], (buf) + ((j) * 512 + t) * 8); gp[j] += 32; } while (0)

  int aoff[4], bhoff[2], bloff[2];
#pragma unroll
  for (int mi = 0; mi < 4; ++mi)
    aoff[mi] = ldsoff_h(wm + mi * 32 + lrow32, khalf);
#pragma unroll
  for (int ni = 0; ni < 2; ++ni) {
    const int rr = wn + ni * 32 + lrow32;
    bhoff[ni] = 8192  + ldsoff_h(rr, khalf);
    bloff[ni] = 16384 + ldsoff_h(rr, khalf);
  }

  f32x16 acc[4][2];
#pragma unroll
  for (int i = 0; i < 4; ++i)
#pragma unroll
    for (int j = 0; j < 2; ++j) acc[i][j] = (f32x16)0.0f;

  _Float16* bufc = sm[0];
  _Float16* bufo = sm[1];
  _Float16* bufn = sm[2];

#pragma unroll
  for (int j = 0; j < 6; ++j) STG1(bufc, j);
#pragma unroll
  for (int j = 0; j < 6; ++j) STG1(bufo, j);
  asm volatile("s_waitcnt vmcnt(6)" ::: "memory");
  __builtin_amdgcn_s_barrier();
  __builtin_amdgcn_sched_barrier(0);

  const int NT = DD / 32;  // 32 K-tiles
#pragma unroll 1
  for (int tt = 0; tt < NT; ++tt) {
    const bool more = (tt + 2 < NT);

    // ---- phase 0 (kk = 0) ----
    {
      f16x8 a[4], bh[2], bl[2];
#pragma unroll
      for (int mi = 0; mi < 4; ++mi) a[mi] = *(const f16x8*)(bufc + aoff[mi]);
#pragma unroll
      for (int ni = 0; ni < 2; ++ni) {
        bh[ni] = *(const f16x8*)(bufc + bhoff[ni]);
        bl[ni] = *(const f16x8*)(bufc + bloff[ni]);
      }
      if (more) { STG1(bufn, 0); STG1(bufn, 1); STG1(bufn, 2); }
      __builtin_amdgcn_s_barrier();
      asm volatile("s_waitcnt lgkmcnt(0)" ::: "memory");
      __builtin_amdgcn_sched_barrier(0);
      __builtin_amdgcn_s_setprio(1);
#pragma unroll
      for (int mi = 0; mi < 4; ++mi)
#pragma unroll
        for (int ni = 0; ni < 2; ++ni) {
          acc[mi][ni] = __builtin_amdgcn_mfma_f32_32x32x16_f16(a[mi], bh[ni], acc[mi][ni], 0, 0, 0);
          acc[mi][ni] = __builtin_amdgcn_mfma_f32_32x32x16_f16(a[mi], bl[ni], acc[mi][ni], 0, 0, 0);
        }
      __builtin_amdgcn_s_setprio(0);
      __builtin_amdgcn_s_barrier();
      __builtin_amdgcn_sched_barrier(0);
    }

    // ---- phase 1 (kk = 1) ----
    {
      f16x8 a[4], bh[2], bl[2];
#pragma unroll
      for (int mi = 0; mi < 4; ++mi) a[mi] = *(const f16x8*)(bufc + 4096 + aoff[mi]);
#pragma unroll
      for (int ni = 0; ni < 2; ++ni) {
        bh[ni] = *(const f16x8*)(bufc + 4096 + bhoff[ni]);
        bl[ni] = *(const f16x8*)(bufc + 4096 + bloff[ni]);
      }
      if (more) { STG1(bufn, 3); STG1(bufn, 4); STG1(bufn, 5); }
      if (more) asm volatile("s_waitcnt vmcnt(6)" ::: "memory");
      else      asm volatile("s_waitcnt vmcnt(0)" ::: "memory");
      __builtin_amdgcn_s_barrier();
      asm volatile("s_waitcnt lgkmcnt(0)" ::: "memory");
      __builtin_amdgcn_sched_barrier(0);
      __builtin_amdgcn_s_setprio(1);
#pragma unroll
      for (int mi = 0; mi < 4; ++mi)
#pragma unroll
        for (int ni = 0; ni < 2; ++ni) {
          acc[mi][ni] = __builtin_amdgcn_mfma_f32_32x32x16_f16(a[mi], bh[ni], acc[mi][ni], 0, 0, 0);
          acc[mi][ni] = __builtin_amdgcn_mfma_f32_32x32x16_f16(a[mi], bl[ni], acc[mi][ni], 0, 0, 0);
        }
      __builtin_amdgcn_s_setprio(0);
      __builtin_amdgcn_s_barrier();
      __builtin_amdgcn_sched_barrier(0);
    }

    _Float16* tmp = bufc; bufc = bufo; bufo = bufn; bufn = tmp;
  }
#undef STG1

  const int rsub = 4 * khalf;
#pragma unroll
  for (int mi = 0; mi < 4; ++mi)
#pragma unroll
    for (int ni = 0; ni < 2; ++ni) {
      const int rb  = tm0 + wm + mi * 32 + rsub;
      const int col = tn0 + wn + ni * 32 + lrow32;
#pragma unroll
      for (int p = 0; p < 16; ++p)
        C[(size_t)(rb + (p & 3) + 8 * (p >> 2)) * SS + col] = acc[mi][ni][p];
    }
}

// ---------------------------------------------------------------------------
// SM: softmax fp32 in place + fp16 weights. 4 rows/block, one wave per row.
// ---------------------------------------------------------------------------
__global__ __launch_bounds__(256)
void attn_softmax_w16(float* __restrict__ w, _Float16* __restrict__ w16) {
  const size_t row = (size_t)blockIdx.x * 4 + (threadIdx.x >> 6);
  const int lane = threadIdx.x & 63;
  float4* p4 = (float4*)(w + row * SS);
  _Float16* o = w16 + row * SS;

  float4 v[8];
#pragma unroll
  for (int j = 0; j < 8; ++j) v[j] = p4[lane + 64 * j];

  float m = -1e30f;
#pragma unroll
  for (int j = 0; j < 8; ++j)
    m = fmaxf(m, fmaxf(fmaxf(v[j].x, v[j].y), fmaxf(v[j].z, v[j].w)));
#pragma unroll
  for (int off = 32; off >= 1; off >>= 1) m = fmaxf(m, __shfl_xor(m, off, 64));

  float s = 0.0f;
#pragma unroll
  for (int j = 0; j < 8; ++j) {
    v[j].x = __expf(v[j].x - m); v[j].y = __expf(v[j].y - m);
    v[j].z = __expf(v[j].z - m); v[j].w = __expf(v[j].w - m);
    s += v[j].x + v[j].y + v[j].z + v[j].w;
  }
#pragma unroll
  for (int off = 32; off >= 1; off >>= 1) s += __shfl_xor(s, off, 64);

  const float inv = __fdividef(1.0f, s);
#pragma unroll
  for (int j = 0; j < 8; ++j) {
    v[j].x *= inv; v[j].y *= inv; v[j].z *= inv; v[j].w *= inv;
    p4[lane + 64 * j] = v[j];
    f16x4 h;
    h[0] = (_Float16)v[j].x; h[1] = (_Float16)v[j].y;
    h[2] = (_Float16)v[j].z; h[3] = (_Float16)v[j].w;
    *(f16x4*)(o + 4 * (lane + 64 * j)) = h;
  }
}

// ---------------------------------------------------------------------------
// G2: context = w16 @ srcT. 128x256 tile -> grid 512 = 2 blocks/CU.
// 8 waves (2Mx4N, per-wave 64x64), BK=32, 64 K-tiles.
// Tri-buffered LDS (A 8KB + B 16KB per buffer = 72 KB total), counted vmcnt.
// Per-buffer layout (halves): A kk0 [0,2048) kk1 [2048,4096),
//                             B kk0 [4096,8192) kk1 [8192,12288).
// ---------------------------------------------------------------------------
__global__ __launch_bounds__(512, 2)
void attn_gemm2_pipe(const _Float16* __restrict__ w16,
                     const _Float16* __restrict__ srcT,
                     float* __restrict__ out) {
  const int b   = blockIdx.z;
  const int tm0 = blockIdx.y * 128;   // t rows
  const int tn0 = blockIdx.x * 256;   // d cols
  float* C = out + (size_t)b * TT * DD;

  __shared__ __align__(16) _Float16 sm[3][12288];   // 72 KB

  const int t      = threadIdx.x;
  const int lane   = t & 63;
  const int wv     = t >> 6;
  const int wm     = (wv >> 2) * 64;   // 0 / 64
  const int wn     = (wv & 3) * 64;    // 0..192
  const int lrow32 = lane & 31;
  const int khalf  = lane >> 5;

  // A staging: 512 chunks (2 kk x 256); thread t covers chunk t.
  const int ccA = t & 255, kkA = t >> 8;
  const int slA = ccA & 7, lnA = ccA >> 3;
  const int rA  = lnA * 4 + (slA >> 1);
  const int hA  = (slA & 1) ^ (lnA & 1);
  const _Float16* gpA = w16 + ((size_t)b * TT + tm0 + rA) * SS + kkA * 16 + hA * 8;
  const int dstA = kkA * 2048 + ccA * 8;

  // B staging: 1024 chunks (2 kk x 512); thread t covers chunks t (kk0), t+512 (kk1).
  const int slB = t & 7, lnB = t >> 3;
  const int rB  = lnB * 4 + (slB >> 1);
  const int hB  = (slB & 1) ^ (lnB & 1);
  const _Float16* gpB0 = srcT + ((size_t)b * DD + tn0 + rB) * SS + hB * 8;
  const _Float16* gpB1 = gpB0 + 16;
  const int dstB0 = 4096 + t * 8;
  const int dstB1 = 8192 + t * 8;

#define STG2(buf)                                      \
  do {                                                 \
    gl2lds16(gpA,  (buf) + dstA);                      \
    gl2lds16(gpB0, (buf) + dstB0);                     \
    gl2lds16(gpB1, (buf) + dstB1);                     \
    gpA += 32; gpB0 += 32; gpB1 += 32;                 \
  } while (0)

  int aoff[2], boff[2];
#pragma unroll
  for (int mi = 0; mi < 2; ++mi)
    aoff[mi] = ldsoff_h(wm + mi * 32 + lrow32, khalf);
#pragma unroll
  for (int ni = 0; ni < 2; ++ni)
    boff[ni] = ldsoff_h(wn + ni * 32 + lrow32, khalf);

  f32x16 acc[2][2];
#pragma unroll
  for (int i = 0; i < 2; ++i)
#pragma unroll
    for (int j = 0; j < 2; ++j) acc[i][j] = (f32x16)0.0f;

  _Float16* bufc = sm[0];
  _Float16* bufo = sm[1];
  _Float16* bufn = sm[2];

  STG2(bufc);
  STG2(bufo);
  asm volatile("s_waitcnt vmcnt(3)" ::: "memory");
  __builtin_amdgcn_s_barrier();
  __builtin_amdgcn_sched_barrier(0);

  const int NT = SS / 32;  // 64 K-tiles
#pragma unroll 1
  for (int tt = 0; tt < NT; ++tt) {
    const bool more = (tt + 2 < NT);
    if (more) STG2(bufn);

#pragma unroll
    for (int kk = 0; kk < 2; ++kk) {
      f16x8 a[2], bf[2];
#pragma unroll
      for (int mi = 0; mi < 2; ++mi)
        a[mi] = *(const f16x8*)(bufc + kk * 2048 + aoff[mi]);
#pragma unroll
      for (int ni = 0; ni < 2; ++ni)
        bf[ni] = *(const f16x8*)(bufc + 4096 + kk * 4096 + boff[ni]);
      __builtin_amdgcn_s_setprio(1);
#pragma unroll
      for (int mi = 0; mi < 2; ++mi)
#pragma unroll
        for (int ni = 0; ni < 2; ++ni)
          acc[mi][ni] = __builtin_amdgcn_mfma_f32_32x32x16_f16(a[mi], bf[ni], acc[mi][ni], 0, 0, 0);
      __builtin_amdgcn_s_setprio(0);
    }

    if (more) asm volatile("s_waitcnt vmcnt(3)" ::: "memory");
    else      asm volatile("s_waitcnt vmcnt(0)" ::: "memory");
    __builtin_amdgcn_s_barrier();
    __builtin_amdgcn_sched_barrier(0);

    _Float16* tmp = bufc; bufc = bufo; bufo = bufn; bufn = tmp;
  }
#undef STG2

  const int rsub = 4 * khalf;
#pragma unroll
  for (int mi = 0; mi < 2; ++mi)
#pragma unroll
    for (int ni = 0; ni < 2; ++ni) {
      const int rb  = tm0 + wm + mi * 32 + rsub;
      const int col = tn0 + wn + ni * 32 + lrow32;
#pragma unroll
      for (int p = 0; p < 16; ++p)
        C[(size_t)(rb + (p & 3) + 8 * (p >> 2)) * DD + col] = acc[mi][ni][p];
    }
}

// ===========================================================================
// Fallback path (round-1 kernels, no workspace).
// ===========================================================================
__global__ __launch_bounds__(256, 1)
void attn_gemm1_scores_bf16x3(const float* __restrict__ trg,
                              const float* __restrict__ src,
                              float* __restrict__ scores) {
  const int b   = blockIdx.z;
  const int tm0 = blockIdx.y * 128;
  const int tn0 = blockIdx.x * 128;
  const float* A  = trg + (size_t)b * TT * DD;
  const float* Bm = src + (size_t)b * SS * DD;
  float* C = scores + (size_t)b * TT * SS;

  __shared__ __align__(16) unsigned short smAh[128 * 32];
  __shared__ __align__(16) unsigned short smAl[128 * 32];
  __shared__ __align__(16) unsigned short smBh[128 * 32];
  __shared__ __align__(16) unsigned short smBl[128 * 32];

  const int t     = threadIdx.x;
  const int lane  = t & 63;
  const int wv    = t >> 6;
  const int m_off = (wv & 1) * 64;
  const int n_off = (wv >> 1) * 64;
  const int q     = lane >> 4;
  const int lrow  = lane & 15;

  f32x4 acc[4][4];
#pragma unroll
  for (int i = 0; i < 4; ++i)
#pragma unroll
    for (int j = 0; j < 4; ++j) acc[i][j] = (f32x4)0.0f;

  for (int kt = 0; kt < DD; kt += 32) {
    __syncthreads();
#pragma unroll
    for (int h = 0; h < 2; ++h) {
      const int c  = t + h * 256;
      const int r  = c >> 2;
      const int j  = c & 3;
      const int gk = j ^ ((r >> 1) & 3);
      {
        const float* ga = A + (size_t)(tm0 + r) * DD + kt + gk * 8;
        float4 v0 = *(const float4*)ga;
        float4 v1 = *(const float4*)(ga + 4);
        float f[8] = {v0.x, v0.y, v0.z, v0.w, v1.x, v1.y, v1.z, v1.w};
        bf16x8 hi, lo;
#pragma unroll
        for (int e = 0; e < 8; ++e) {
          unsigned short hb = bf16_rne(f[e]);
          hi[e] = (short)hb;
          float hf = __uint_as_float(((unsigned int)hb) << 16);
          lo[e] = (short)bf16_rne(f[e] - hf);
        }
        *(bf16x8*)(smAh + c * 8) = hi;
        *(bf16x8*)(smAl + c * 8) = lo;
      }
      {
        const float* gb = Bm + (size_t)(tn0 + r) * DD + kt + gk * 8;
        float4 v0 = *(const float4*)gb;
        float4 v1 = *(const float4*)(gb + 4);
        float f[8] = {v0.x, v0.y, v0.z, v0.w, v1.x, v1.y, v1.z, v1.w};
        bf16x8 hi, lo;
#pragma unroll
        for (int e = 0; e < 8; ++e) {
          unsigned short hb = bf16_rne(f[e]);
          hi[e] = (short)hb;
          float hf = __uint_as_float(((unsigned int)hb) << 16);
          lo[e] = (short)bf16_rne(f[e] - hf);
        }
        *(bf16x8*)(smBh + c * 8) = hi;
        *(bf16x8*)(smBl + c * 8) = lo;
      }
    }
    __syncthreads();

    bf16x8 ah[4], al[4], bh[4], bl[4];
#pragma unroll
    for (int mi = 0; mi < 4; ++mi) {
      const int r   = m_off + mi * 16 + lrow;
      const int off = (r * 4 + (q ^ ((r >> 1) & 3))) * 8;
      ah[mi] = *(const bf16x8*)(smAh + off);
      al[mi] = *(const bf16x8*)(smAl + off);
    }
#pragma unroll
    for (int ni = 0; ni < 4; ++ni) {
      const int r   = n_off + ni * 16 + lrow;
      const int off = (r * 4 + (q ^ ((r >> 1) & 3))) * 8;
      bh[ni] = *(const bf16x8*)(smBh + off);
      bl[ni] = *(const bf16x8*)(smBl + off);
    }
#pragma unroll
    for (int mi = 0; mi < 4; ++mi)
#pragma unroll
      for (int ni = 0; ni < 4; ++ni) {
        acc[mi][ni] = __builtin_amdgcn_mfma_f32_16x16x32_bf16(al[mi], bh[ni], acc[mi][ni], 0, 0, 0);
        acc[mi][ni] = __builtin_amdgcn_mfma_f32_16x16x32_bf16(ah[mi], bl[ni], acc[mi][ni], 0, 0, 0);
        acc[mi][ni] = __builtin_amdgcn_mfma_f32_16x16x32_bf16(ah[mi], bh[ni], acc[mi][ni], 0, 0, 0);
      }
  }

#pragma unroll
  for (int mi = 0; mi < 4; ++mi)
#pragma unroll
    for (int ni = 0; ni < 4; ++ni) {
      const int row0 = tm0 + m_off + mi * 16 + q * 4;
      const int col  = tn0 + n_off + ni * 16 + lrow;
#pragma unroll
      for (int p = 0; p < 4; ++p)
        C[(size_t)(row0 + p) * SS + col] = acc[mi][ni][p];
    }
}

__global__ __launch_bounds__(256)
void attn_softmax_rows(float* __restrict__ w) {
  float* p = w + (size_t)blockIdx.x * SS;
  const int t = threadIdx.x;
  float4* p4 = (float4*)p;
  float4 v0 = p4[t];
  float4 v1 = p4[t + 256];

  float m = fmaxf(fmaxf(fmaxf(v0.x, v0.y), fmaxf(v0.z, v0.w)),
                  fmaxf(fmaxf(v1.x, v1.y), fmaxf(v1.z, v1.w)));
#pragma unroll
  for (int off = 32; off >= 1; off >>= 1) m = fmaxf(m, __shfl_xor(m, off, 64));
  __shared__ float redm[4];
  __shared__ float reds[4];
  const int wv = t >> 6, lane = t & 63;
  if (lane == 0) redm[wv] = m;
  __syncthreads();
  m = fmaxf(fmaxf(redm[0], redm[1]), fmaxf(redm[2], redm[3]));

  v0.x = __expf(v0.x - m); v0.y = __expf(v0.y - m);
  v0.z = __expf(v0.z - m); v0.w = __expf(v0.w - m);
  v1.x = __expf(v1.x - m); v1.y = __expf(v1.y - m);
  v1.z = __expf(v1.z - m); v1.w = __expf(v1.w - m);

  float s = v0.x + v0.y + v0.z + v0.w + v1.x + v1.y + v1.z + v1.w;
#pragma unroll
  for (int off = 32; off >= 1; off >>= 1) s += __shfl_xor(s, off, 64);
  if (lane == 0) reds[wv] = s;
  __syncthreads();
  s = reds[0] + reds[1] + reds[2] + reds[3];

  const float inv = __fdividef(1.0f, s);
  v0.x *= inv; v0.y *= inv; v0.z *= inv; v0.w *= inv;
  v1.x *= inv; v1.y *= inv; v1.z *= inv; v1.w *= inv;
  p4[t] = v0;
  p4[t + 256] = v1;
}

__global__ __launch_bounds__(256, 1)
void attn_gemm2_ctx_f16(const float* __restrict__ w,
                        const float* __restrict__ src,
                        float* __restrict__ out) {
  const int b   = blockIdx.z;
  const int tm0 = blockIdx.y * 128;
  const int tn0 = blockIdx.x * 128;
  const float* A  = w + (size_t)b * TT * SS;
  const float* Bs = src + (size_t)b * SS * DD;
  float* C = out + (size_t)b * TT * DD;

  __shared__ __align__(16) _Float16 smA[128 * 32];
  __shared__ __align__(16) _Float16 smB[128 * 32];

  const int t     = threadIdx.x;
  const int lane  = t & 63;
  const int wv    = t >> 6;
  const int m_off = (wv & 1) * 64;
  const int n_off = (wv >> 1) * 64;
  const int q     = lane >> 4;
  const int lrow  = lane & 15;

  const int bn    = t & 127;
  const int bh2   = t >> 7;
  const int bs2   = (bn >> 1) & 3;
  const int slot0 = (2 * bh2) ^ bs2;
  const int slot1 = (2 * bh2 + 1) ^ bs2;

  f32x4 acc[4][4];
#pragma unroll
  for (int i = 0; i < 4; ++i)
#pragma unroll
    for (int j = 0; j < 4; ++j) acc[i][j] = (f32x4)0.0f;

  for (int kt = 0; kt < SS; kt += 32) {
    __syncthreads();
#pragma unroll
    for (int h = 0; h < 2; ++h) {
      const int c  = t + h * 256;
      const int r  = c >> 2;
      const int j  = c & 3;
      const int gk = j ^ ((r >> 1) & 3);
      const float* ga = A + (size_t)(tm0 + r) * SS + kt + gk * 8;
      float4 v0 = *(const float4*)ga;
      float4 v1 = *(const float4*)(ga + 4);
      f16x8 hv;
      hv[0] = (_Float16)v0.x; hv[1] = (_Float16)v0.y;
      hv[2] = (_Float16)v0.z; hv[3] = (_Float16)v0.w;
      hv[4] = (_Float16)v1.x; hv[5] = (_Float16)v1.y;
      hv[6] = (_Float16)v1.z; hv[7] = (_Float16)v1.w;
      *(f16x8*)(smA + c * 8) = hv;
    }
    {
      const float* gb = Bs + (size_t)(kt + bh2 * 16) * DD + (tn0 + bn);
      f16x8 c0, c1;
#pragma unroll
      for (int kk = 0; kk < 8; ++kk) c0[kk] = (_Float16)gb[(size_t)kk * DD];
#pragma unroll
      for (int kk = 0; kk < 8; ++kk) c1[kk] = (_Float16)gb[(size_t)(kk + 8) * DD];
      *(f16x8*)(smB + bn * 32 + slot0 * 8) = c0;
      *(f16x8*)(smB + bn * 32 + slot1 * 8) = c1;
    }
    __syncthreads();

    f16x8 af[4], bfr[4];
#pragma unroll
    for (int mi = 0; mi < 4; ++mi) {
      const int r   = m_off + mi * 16 + lrow;
      const int off = (r * 4 + (q ^ ((r >> 1) & 3))) * 8;
      af[mi] = *(const f16x8*)(smA + off);
    }
#pragma unroll
    for (int ni = 0; ni < 4; ++ni) {
      const int n   = n_off + ni * 16 + lrow;
      const int off = n * 32 + (q ^ ((n >> 1) & 3)) * 8;
      bfr[ni] = *(const f16x8*)(smB + off);
    }
#pragma unroll
    for (int mi = 0; mi < 4; ++mi)
#pragma unroll
      for (int ni = 0; ni < 4; ++ni)
        acc[mi][ni] = __builtin_amdgcn_mfma_f32_16x16x32_f16(af[mi], bfr[ni], acc[mi][ni], 0, 0, 0);
  }

#pragma unroll
  for (int mi = 0; mi < 4; ++mi)
#pragma unroll
    for (int ni = 0; ni < 4; ++ni) {
      const int row0 = tm0 + m_off + mi * 16 + q * 4;
      const int col  = tn0 + n_off + ni * 16 + lrow;
#pragma unroll
      for (int p = 0; p < 4; ++p)
        C[(size_t)(row0 + p) * DD + col] = acc[mi][ni][p];
    }
}

extern "C" void kernel_launch(void* const* d_in, const int* in_sizes, int n_in,
                              void* d_out, int out_size, void* d_ws, size_t ws_size,
                              hipStream_t stream) {
  const float* trg = (const float*)d_in[0];
  const float* src = (const float*)d_in[1];
  float* ctx = (float*)d_out;
  float* wts = (float*)d_out + (size_t)BB * TT * DD;

  const size_t NT = (size_t)BB * TT * DD;  // 16,777,216
  const size_t NW = (size_t)BB * TT * SS;  // 33,554,432
  const size_t need = (4 * NT + NW) * 2;   // 201,326,592 B = 192 MiB

  if (ws_size >= need) {
    _Float16* tH16 = (_Float16*)d_ws;
    _Float16* sH16 = tH16 + NT;
    _Float16* sL16 = sH16 + NT;
    _Float16* srcT = sL16 + NT;
    _Float16* w16  = srcT + NT;

    conv_trg_f16<<<dim3(NT / (8 * 256)), 256, 0, stream>>>(trg, tH16);
    conv_src_f16_hilo_t<<<dim3(DD / 64, SS / 64, BB), 256, 0, stream>>>(src, sH16, sL16, srcT);
    attn_gemm1_pipe<<<dim3(SS / 256, TT / 256, BB), 512, 0, stream>>>(tH16, sH16, sL16, wts);
    attn_softmax_w16<<<dim3(BB * TT / 4), 256, 0, stream>>>(wts, w16);
    attn_gemm2_pipe<<<dim3(DD / 256, TT / 128, BB), 512, 0, stream>>>(w16, srcT, ctx);
  } else {
    attn_gemm1_scores_bf16x3<<<dim3(SS / 128, TT / 128, BB), 256, 0, stream>>>(trg, src, wts);
    attn_softmax_rows<<<dim3(BB * TT), 256, 0, stream>>>(wts);
    attn_gemm2_ctx_f16<<<dim3(DD / 128, TT / 128, BB), 256, 0, stream>>>(wts, src, ctx);
  }
}

// Round 7
// 557.851 us; speedup vs baseline: 1.0278x; 1.0278x over previous
//
#include <hip/hip_runtime.h>

// Luong dot attention, B=8, T=S=2048, D=1024, fp32 in/out.
// Fast path (ws >= 192 MiB):
//   P1: trg -> fp16
//   P2: src -> fp16 hi + fp16 lo ([S][D]) + fp16 transposed hi ([D][S])
//   G1: scores = trg16 @ (srcHi+srcLo)^T, fp16 2-pass, 256x256 tile, BK=32,
//       tri-buffered LDS, counted vmcnt + counted-lgkm fragment pipeline
//   SM: softmax fp32 in place + fp16 weights (single-wave blocks)
//   G2: context = w16 @ srcT, 256x256 tile, same pipelined structure
// Fallback = round-1 kernels.

#define BB 8
#define TT 2048
#define SS 2048
#define DD 1024

typedef float  f32x4   __attribute__((ext_vector_type(4)));
typedef float  f32x16  __attribute__((ext_vector_type(16)));
typedef short  bf16x8  __attribute__((ext_vector_type(8)));
typedef _Float16 f16x8 __attribute__((ext_vector_type(8)));
typedef _Float16 f16x4 __attribute__((ext_vector_type(4)));

static __device__ __forceinline__ unsigned short bf16_rne(float x) {
  unsigned int u = __float_as_uint(x);
  u += 0x7FFFu + ((u >> 16) & 1u);
  return (unsigned short)(u >> 16);
}

static __device__ __forceinline__ void gl2lds16(const void* g, void* l) {
  __builtin_amdgcn_global_load_lds(
      (const __attribute__((address_space(1))) unsigned int*)g,
      (__attribute__((address_space(3))) unsigned int*)l, 16, 0, 0);
}

// Bank-perfect LDS layout for an [R]x16-half region.
// Row r, half h: halves offset = (r>>2)*64 + (2*(r&3) + (h ^ ((r>>2)&1)))*8.
static __device__ __forceinline__ int ldsoff_h(int r, int h) {
  return ((r >> 2) << 6) + ((((r & 3) << 1) + (h ^ ((r >> 2) & 1))) << 3);
}

// ---------------------------------------------------------------------------
// P1: trg fp32 -> fp16 (single).
// ---------------------------------------------------------------------------
__global__ __launch_bounds__(256)
void conv_trg_f16(const float* __restrict__ x, _Float16* __restrict__ h16) {
  const size_t i = ((size_t)blockIdx.x * 256 + threadIdx.x) * 8;
  float4 v0 = *(const float4*)(x + i);
  float4 v1 = *(const float4*)(x + i + 4);
  f16x8 h;
  h[0] = (_Float16)v0.x; h[1] = (_Float16)v0.y;
  h[2] = (_Float16)v0.z; h[3] = (_Float16)v0.w;
  h[4] = (_Float16)v1.x; h[5] = (_Float16)v1.y;
  h[6] = (_Float16)v1.z; h[7] = (_Float16)v1.w;
  *(f16x8*)(h16 + i) = h;
}

// ---------------------------------------------------------------------------
// P2: src fp32 -> fp16 hi + fp16 lo ([S][D]) + fp16 transposed hi ([D][S]).
// ---------------------------------------------------------------------------
__global__ __launch_bounds__(256)
void conv_src_f16_hilo_t(const float* __restrict__ src,
                         _Float16* __restrict__ hi,
                         _Float16* __restrict__ lo,
                         _Float16* __restrict__ srcT) {
  const int b  = blockIdx.z;
  const int d0 = blockIdx.x * 64;
  const int s0 = blockIdx.y * 64;
  const float* S = src + (size_t)b * SS * DD;
  __shared__ _Float16 t16[64][65];
  const int t = threadIdx.x;

#pragma unroll
  for (int p = 0; p < 4; ++p) {
    const int r = p * 16 + (t >> 4);
    const int c = (t & 15) * 4;
    float4 v = *(const float4*)(S + (size_t)(s0 + r) * DD + d0 + c);
    float f[4] = {v.x, v.y, v.z, v.w};
    f16x4 h, l;
#pragma unroll
    for (int e = 0; e < 4; ++e) {
      _Float16 hv = (_Float16)f[e];
      h[e] = hv;
      l[e] = (_Float16)(f[e] - (float)hv);
      t16[r][c + e] = hv;
    }
    const size_t go = ((size_t)b * SS + s0 + r) * DD + d0 + c;
    *(f16x4*)(hi + go) = h;
    *(f16x4*)(lo + go) = l;
  }
  __syncthreads();
#pragma unroll
  for (int p = 0; p < 4; ++p) {
    const int d  = p * 16 + (t >> 4);
    const int sq = (t & 15) * 4;
    f16x4 o;
#pragma unroll
    for (int k = 0; k < 4; ++k) o[k] = t16[sq + k][d];
    *(f16x4*)(srcT + ((size_t)b * DD + d0 + d) * SS + s0 + sq) = o;
  }
}

// ---------------------------------------------------------------------------
// G1: scores = trg16 @ src16^T, fp16 2-pass (A single, B hi+lo).
// 256x256 tile, BK=32, 8 waves (2Mx4N, per-wave 128x64), 32x32x16 MFMA.
// Tri-buffered LDS; per K-tile: issue stage + p1 ds_reads, lgkm(8) -> MFMA p0
// (hides p1 LDS latency), lgkm(0) -> MFMA p1, counted vmcnt + barrier,
// then issue next tile's p0 ds_reads.
// ---------------------------------------------------------------------------
__global__ __launch_bounds__(512, 2)
void attn_gemm1_pipe(const _Float16* __restrict__ a16,
                     const _Float16* __restrict__ bh16,
                     const _Float16* __restrict__ bl16,
                     float* __restrict__ scores) {
  const int b   = blockIdx.z;
  const int tm0 = blockIdx.y * 256;
  const int tn0 = blockIdx.x * 256;
  float* C = scores + (size_t)b * TT * SS;

  __shared__ __align__(16) _Float16 sm[3][24576];   // 144 KB

  const int t      = threadIdx.x;            // 0..511
  const int lane   = t & 63;
  const int wv     = t >> 6;                 // 0..7
  const int wm     = (wv >> 2) * 128;        // 0 / 128
  const int wn     = (wv & 3) * 64;          // 0..192
  const int lrow32 = lane & 31;
  const int khalf  = lane >> 5;

  // staging: 3072 16B-chunks per buffer; thread t covers chunks j*512+t.
  const _Float16* gp[6];
  {
    const _Float16* base0 = a16  + ((size_t)b * TT + tm0) * DD;
    const _Float16* base1 = bh16 + ((size_t)b * SS + tn0) * DD;
    const _Float16* base2 = bl16 + ((size_t)b * SS + tn0) * DD;
    const _Float16* bases[3] = {base0, base1, base2};
#pragma unroll
    for (int j = 0; j < 6; ++j) {
      const int kk   = j & 1;
      const int cc   = t;
      const int line = cc >> 3, slot = cc & 7;
      const int r    = (line << 2) + (slot >> 1);
      const int h    = (slot & 1) ^ (line & 1);
      gp[j] = bases[j >> 1] + (size_t)r * DD + kk * 16 + h * 8;
    }
  }
#define STG1(buf, j) do { gl2lds16(gp[j], (buf) + ((j) * 512 + t) * 8); gp[j] += 32; } while (0)

  int aoff[4], bhoff[2], bloff[2];
#pragma unroll
  for (int mi = 0; mi < 4; ++mi)
    aoff[mi] = ldsoff_h(wm + mi * 32 + lrow32, khalf);
#pragma unroll
  for (int ni = 0; ni < 2; ++ni) {
    const int rr = wn + ni * 32 + lrow32;
    bhoff[ni] = 8192  + ldsoff_h(rr, khalf);
    bloff[ni] = 16384 + ldsoff_h(rr, khalf);
  }

  f32x16 acc[4][2];
#pragma unroll
  for (int i = 0; i < 2; ++i) {}
#pragma unroll
  for (int i = 0; i < 4; ++i)
#pragma unroll
    for (int j = 0; j < 2; ++j) acc[i][j] = (f32x16)0.0f;

  // double-buffered fragment registers
  f16x8 a0[4], bh0[2], bl0[2];
  f16x8 a1[4], bh1[2], bl1[2];

  _Float16* bufc = sm[0];
  _Float16* bufo = sm[1];
  _Float16* bufn = sm[2];

#define G1_READ_P0()                                                        \
  do {                                                                      \
    _Pragma("unroll") for (int mi = 0; mi < 4; ++mi)                        \
      a0[mi] = *(const f16x8*)(bufc + aoff[mi]);                            \
    _Pragma("unroll") for (int ni = 0; ni < 2; ++ni) {                      \
      bh0[ni] = *(const f16x8*)(bufc + bhoff[ni]);                          \
      bl0[ni] = *(const f16x8*)(bufc + bloff[ni]);                          \
    }                                                                       \
  } while (0)

#define G1_READ_P1()                                                        \
  do {                                                                      \
    _Pragma("unroll") for (int mi = 0; mi < 4; ++mi)                        \
      a1[mi] = *(const f16x8*)(bufc + 4096 + aoff[mi]);                     \
    _Pragma("unroll") for (int ni = 0; ni < 2; ++ni) {                      \
      bh1[ni] = *(const f16x8*)(bufc + 4096 + bhoff[ni]);                   \
      bl1[ni] = *(const f16x8*)(bufc + 4096 + bloff[ni]);                   \
    }                                                                       \
  } while (0)

#define G1_MFMA(AA, BH, BL)                                                 \
  do {                                                                      \
    __builtin_amdgcn_s_setprio(1);                                          \
    _Pragma("unroll") for (int mi = 0; mi < 4; ++mi)                        \
      _Pragma("unroll") for (int ni = 0; ni < 2; ++ni) {                    \
        acc[mi][ni] = __builtin_amdgcn_mfma_f32_32x32x16_f16(AA[mi], BH[ni], acc[mi][ni], 0, 0, 0); \
        acc[mi][ni] = __builtin_amdgcn_mfma_f32_32x32x16_f16(AA[mi], BL[ni], acc[mi][ni], 0, 0, 0); \
      }                                                                     \
    __builtin_amdgcn_s_setprio(0);                                          \
  } while (0)

  // prologue: tiles 0 and 1 in flight; wait for tile 0 only.
#pragma unroll
  for (int j = 0; j < 6; ++j) STG1(bufc, j);
#pragma unroll
  for (int j = 0; j < 6; ++j) STG1(bufo, j);
  asm volatile("s_waitcnt vmcnt(6)" ::: "memory");
  __builtin_amdgcn_s_barrier();
  __builtin_amdgcn_sched_barrier(0);
  G1_READ_P0();                       // tile 0 phase-0 frags (8 ds_reads)
  __builtin_amdgcn_sched_barrier(0);

  const int NT = DD / 32;  // 32 K-tiles
#pragma unroll 1
  for (int tt = 0; tt < NT; ++tt) {
    const bool more = (tt + 2 < NT);

    if (more) { STG1(bufn, 0); STG1(bufn, 1); STG1(bufn, 2);
                STG1(bufn, 3); STG1(bufn, 4); STG1(bufn, 5); }
    G1_READ_P1();                     // 8 ds_reads in flight behind p0's
    asm volatile("s_waitcnt lgkmcnt(8)" ::: "memory");   // p0 ready
    __builtin_amdgcn_sched_barrier(0);
    G1_MFMA(a0, bh0, bl0);            // hides p1 LDS latency
    asm volatile("s_waitcnt lgkmcnt(0)" ::: "memory");   // p1 ready
    __builtin_amdgcn_sched_barrier(0);
    G1_MFMA(a1, bh1, bl1);

    if (more) asm volatile("s_waitcnt vmcnt(6)" ::: "memory");
    else      asm volatile("s_waitcnt vmcnt(0)" ::: "memory");
    __builtin_amdgcn_s_barrier();
    __builtin_amdgcn_sched_barrier(0);

    _Float16* tmp = bufc; bufc = bufo; bufo = bufn; bufn = tmp;
    if (tt + 1 < NT) {
      G1_READ_P0();                   // next tile phase-0 frags (8 ds_reads)
      __builtin_amdgcn_sched_barrier(0);
    }
  }
#undef G1_MFMA
#undef G1_READ_P1
#undef G1_READ_P0
#undef STG1

  // C/D 32x32: col=lane&31, row=(p&3)+8*(p>>2)+4*(lane>>5)
  const int rsub = 4 * khalf;
#pragma unroll
  for (int mi = 0; mi < 4; ++mi)
#pragma unroll
    for (int ni = 0; ni < 2; ++ni) {
      const int rb  = tm0 + wm + mi * 32 + rsub;
      const int col = tn0 + wn + ni * 32 + lrow32;
#pragma unroll
      for (int p = 0; p < 16; ++p)
        C[(size_t)(rb + (p & 3) + 8 * (p >> 2)) * SS + col] = acc[mi][ni][p];
    }
}

// ---------------------------------------------------------------------------
// SM: single-wave blocks. 32 floats/lane, shuffle-only.
// ---------------------------------------------------------------------------
__global__ __launch_bounds__(64)
void attn_softmax_w16(float* __restrict__ w, _Float16* __restrict__ w16) {
  const size_t row = blockIdx.x;
  float4* p4 = (float4*)(w + row * SS);
  _Float16* o = w16 + row * SS;
  const int lane = threadIdx.x;

  float4 v[8];
#pragma unroll
  for (int j = 0; j < 8; ++j) v[j] = p4[lane + 64 * j];

  float m = -1e30f;
#pragma unroll
  for (int j = 0; j < 8; ++j)
    m = fmaxf(m, fmaxf(fmaxf(v[j].x, v[j].y), fmaxf(v[j].z, v[j].w)));
#pragma unroll
  for (int off = 32; off >= 1; off >>= 1) m = fmaxf(m, __shfl_xor(m, off, 64));

  float s = 0.0f;
#pragma unroll
  for (int j = 0; j < 8; ++j) {
    v[j].x = __expf(v[j].x - m); v[j].y = __expf(v[j].y - m);
    v[j].z = __expf(v[j].z - m); v[j].w = __expf(v[j].w - m);
    s += v[j].x + v[j].y + v[j].z + v[j].w;
  }
#pragma unroll
  for (int off = 32; off >= 1; off >>= 1) s += __shfl_xor(s, off, 64);

  const float inv = __fdividef(1.0f, s);
#pragma unroll
  for (int j = 0; j < 8; ++j) {
    v[j].x *= inv; v[j].y *= inv; v[j].z *= inv; v[j].w *= inv;
    p4[lane + 64 * j] = v[j];
    f16x4 h;
    h[0] = (_Float16)v[j].x; h[1] = (_Float16)v[j].y;
    h[2] = (_Float16)v[j].z; h[3] = (_Float16)v[j].w;
    *(f16x4*)(o + 4 * (lane + 64 * j)) = h;
  }
}

// ---------------------------------------------------------------------------
// G2: context = w16 @ srcT. 256x256 tile, BK=32, 64 K-tiles, same counted-lgkm
// fragment pipeline as G1. Per-buffer layout (halves):
// A kk0 [0,4096) kk1 [4096,8192), B kk0 [8192,12288) kk1 [12288,16384).
// ---------------------------------------------------------------------------
__global__ __launch_bounds__(512, 2)
void attn_gemm2_pipe(const _Float16* __restrict__ w16,
                     const _Float16* __restrict__ srcT,
                     float* __restrict__ out) {
  const int b   = blockIdx.z;
  const int tm0 = blockIdx.y * 256;
  const int tn0 = blockIdx.x * 256;
  float* C = out + (size_t)b * TT * DD;

  __shared__ __align__(16) _Float16 sm[3][16384];   // 96 KB

  const int t      = threadIdx.x;
  const int lane   = t & 63;
  const int wv     = t >> 6;
  const int wm     = (wv >> 2) * 128;
  const int wn     = (wv & 3) * 64;
  const int lrow32 = lane & 31;
  const int khalf  = lane >> 5;

  const _Float16* gp[4];
  {
    const _Float16* base0 = w16  + ((size_t)b * TT + tm0) * SS;
    const _Float16* base1 = srcT + ((size_t)b * DD + tn0) * SS;
    const _Float16* bases[2] = {base0, base1};
#pragma unroll
    for (int j = 0; j < 4; ++j) {
      const int kk   = j & 1;
      const int cc   = t;
      const int line = cc >> 3, slot = cc & 7;
      const int r    = (line << 2) + (slot >> 1);
      const int h    = (slot & 1) ^ (line & 1);
      gp[j] = bases[j >> 1] + (size_t)r * SS + kk * 16 + h * 8;
    }
  }
#define STG2(buf, j) do { gl2lds16(gp[j], (buf) + ((j) * 512 + t) * 8); gp[j] += 32; } while (0)

  int aoff[4], boff[2];
#pragma unroll
  for (int mi = 0; mi < 4; ++mi)
    aoff[mi] = ldsoff_h(wm + mi * 32 + lrow32, khalf);
#pragma unroll
  for (int ni = 0; ni < 2; ++ni)
    boff[ni] = 8192 + ldsoff_h(wn + ni * 32 + lrow32, khalf);

  f32x16 acc[4][2];
#pragma unroll
  for (int i = 0; i < 4; ++i)
#pragma unroll
    for (int j = 0; j < 2; ++j) acc[i][j] = (f32x16)0.0f;

  f16x8 a0[4], b0[2];
  f16x8 a1[4], b1[2];

  _Float16* bufc = sm[0];
  _Float16* bufo = sm[1];
  _Float16* bufn = sm[2];

#define G2_READ_P0()                                                        \
  do {                                                                      \
    _Pragma("unroll") for (int mi = 0; mi < 4; ++mi)                        \
      a0[mi] = *(const f16x8*)(bufc + aoff[mi]);                            \
    _Pragma("unroll") for (int ni = 0; ni < 2; ++ni)                        \
      b0[ni] = *(const f16x8*)(bufc + boff[ni]);                            \
  } while (0)

#define G2_READ_P1()                                                        \
  do {                                                                      \
    _Pragma("unroll") for (int mi = 0; mi < 4; ++mi)                        \
      a1[mi] = *(const f16x8*)(bufc + 4096 + aoff[mi]);                     \
    _Pragma("unroll") for (int ni = 0; ni < 2; ++ni)                        \
      b1[ni] = *(const f16x8*)(bufc + 4096 + boff[ni]);                     \
  } while (0)

#define G2_MFMA(AA, BF)                                                     \
  do {                                                                      \
    __builtin_amdgcn_s_setprio(1);                                          \
    _Pragma("unroll") for (int mi = 0; mi < 4; ++mi)                        \
      _Pragma("unroll") for (int ni = 0; ni < 2; ++ni)                      \
        acc[mi][ni] = __builtin_amdgcn_mfma_f32_32x32x16_f16(AA[mi], BF[ni], acc[mi][ni], 0, 0, 0); \
    __builtin_amdgcn_s_setprio(0);                                          \
  } while (0)

#pragma unroll
  for (int j = 0; j < 4; ++j) STG2(bufc, j);
#pragma unroll
  for (int j = 0; j < 4; ++j) STG2(bufo, j);
  asm volatile("s_waitcnt vmcnt(4)" ::: "memory");
  __builtin_amdgcn_s_barrier();
  __builtin_amdgcn_sched_barrier(0);
  G2_READ_P0();
  __builtin_amdgcn_sched_barrier(0);

  const int NT = SS / 32;  // 64 K-tiles
#pragma unroll 1
  for (int tt = 0; tt < NT; ++tt) {
    const bool more = (tt + 2 < NT);

    if (more) { STG2(bufn, 0); STG2(bufn, 1); STG2(bufn, 2); STG2(bufn, 3); }
    G2_READ_P1();                     // 6 ds_reads behind p0's
    asm volatile("s_waitcnt lgkmcnt(6)" ::: "memory");   // p0 ready
    __builtin_amdgcn_sched_barrier(0);
    G2_MFMA(a0, b0);
    asm volatile("s_waitcnt lgkmcnt(0)" ::: "memory");   // p1 ready
    __builtin_amdgcn_sched_barrier(0);
    G2_MFMA(a1, b1);

    if (more) asm volatile("s_waitcnt vmcnt(4)" ::: "memory");
    else      asm volatile("s_waitcnt vmcnt(0)" ::: "memory");
    __builtin_amdgcn_s_barrier();
    __builtin_amdgcn_sched_barrier(0);

    _Float16* tmp = bufc; bufc = bufo; bufo = bufn; bufn = tmp;
    if (tt + 1 < NT) {
      G2_READ_P0();
      __builtin_amdgcn_sched_barrier(0);
    }
  }
#undef G2_MFMA
#undef G2_READ_P1
#undef G2_READ_P0
#undef STG2

  const int rsub = 4 * khalf;
#pragma unroll
  for (int mi = 0; mi < 4; ++mi)
#pragma unroll
    for (int ni = 0; ni < 2; ++ni) {
      const int rb  = tm0 + wm + mi * 32 + rsub;
      const int col = tn0 + wn + ni * 32 + lrow32;
#pragma unroll
      for (int p = 0; p < 16; ++p)
        C[(size_t)(rb + (p & 3) + 8 * (p >> 2)) * DD + col] = acc[mi][ni][p];
    }
}

// ===========================================================================
// Fallback path (round-1 kernels, no workspace).
// ===========================================================================
__global__ __launch_bounds__(256, 1)
void attn_gemm1_scores_bf16x3(const float* __restrict__ trg,
                              const float* __restrict__ src,
                              float* __restrict__ scores) {
  const int b   = blockIdx.z;
  const int tm0 = blockIdx.y * 128;
  const int tn0 = blockIdx.x * 128;
  const float* A  = trg + (size_t)b * TT * DD;
  const float* Bm = src + (size_t)b * SS * DD;
  float* C = scores + (size_t)b * TT * SS;

  __shared__ __align__(16) unsigned short smAh[128 * 32];
  __shared__ __align__(16) unsigned short smAl[128 * 32];
  __shared__ __align__(16) unsigned short smBh[128 * 32];
  __shared__ __align__(16) unsigned short smBl[128 * 32];

  const int t     = threadIdx.x;
  const int lane  = t & 63;
  const int wv    = t >> 6;
  const int m_off = (wv & 1) * 64;
  const int n_off = (wv >> 1) * 64;
  const int q     = lane >> 4;
  const int lrow  = lane & 15;

  f32x4 acc[4][4];
#pragma unroll
  for (int i = 0; i < 4; ++i)
#pragma unroll
    for (int j = 0; j < 4; ++j) acc[i][j] = (f32x4)0.0f;

  for (int kt = 0; kt < DD; kt += 32) {
    __syncthreads();
#pragma unroll
    for (int h = 0; h < 2; ++h) {
      const int c  = t + h * 256;
      const int r  = c >> 2;
      const int j  = c & 3;
      const int gk = j ^ ((r >> 1) & 3);
      {
        const float* ga = A + (size_t)(tm0 + r) * DD + kt + gk * 8;
        float4 v0 = *(const float4*)ga;
        float4 v1 = *(const float4*)(ga + 4);
        float f[8] = {v0.x, v0.y, v0.z, v0.w, v1.x, v1.y, v1.z, v1.w};
        bf16x8 hi, lo;
#pragma unroll
        for (int e = 0; e < 8; ++e) {
          unsigned short hb = bf16_rne(f[e]);
          hi[e] = (short)hb;
          float hf = __uint_as_float(((unsigned int)hb) << 16);
          lo[e] = (short)bf16_rne(f[e] - hf);
        }
        *(bf16x8*)(smAh + c * 8) = hi;
        *(bf16x8*)(smAl + c * 8) = lo;
      }
      {
        const float* gb = Bm + (size_t)(tn0 + r) * DD + kt + gk * 8;
        float4 v0 = *(const float4*)gb;
        float4 v1 = *(const float4*)(gb + 4);
        float f[8] = {v0.x, v0.y, v0.z, v0.w, v1.x, v1.y, v1.z, v1.w};
        bf16x8 hi, lo;
#pragma unroll
        for (int e = 0; e < 8; ++e) {
          unsigned short hb = bf16_rne(f[e]);
          hi[e] = (short)hb;
          float hf = __uint_as_float(((unsigned int)hb) << 16);
          lo[e] = (short)bf16_rne(f[e] - hf);
        }
        *(bf16x8*)(smBh + c * 8) = hi;
        *(bf16x8*)(smBl + c * 8) = lo;
      }
    }
    __syncthreads();

    bf16x8 ah[4], al[4], bh[4], bl[4];
#pragma unroll
    for (int mi = 0; mi < 4; ++mi) {
      const int r   = m_off + mi * 16 + lrow;
      const int off = (r * 4 + (q ^ ((r >> 1) & 3))) * 8;
      ah[mi] = *(const bf16x8*)(smAh + off);
      al[mi] = *(const bf16x8*)(smAl + off);
    }
#pragma unroll
    for (int ni = 0; ni < 4; ++ni) {
      const int r   = n_off + ni * 16 + lrow;
      const int off = (r * 4 + (q ^ ((r >> 1) & 3))) * 8;
      bh[ni] = *(const bf16x8*)(smBh + off);
      bl[ni] = *(const bf16x8*)(smBl + off);
    }
#pragma unroll
    for (int mi = 0; mi < 4; ++mi)
#pragma unroll
      for (int ni = 0; ni < 4; ++ni) {
        acc[mi][ni] = __builtin_amdgcn_mfma_f32_16x16x32_bf16(al[mi], bh[ni], acc[mi][ni], 0, 0, 0);
        acc[mi][ni] = __builtin_amdgcn_mfma_f32_16x16x32_bf16(ah[mi], bl[ni], acc[mi][ni], 0, 0, 0);
        acc[mi][ni] = __builtin_amdgcn_mfma_f32_16x16x32_bf16(ah[mi], bh[ni], acc[mi][ni], 0, 0, 0);
      }
  }

#pragma unroll
  for (int mi = 0; mi < 4; ++mi)
#pragma unroll
    for (int ni = 0; ni < 4; ++ni) {
      const int row0 = tm0 + m_off + mi * 16 + q * 4;
      const int col  = tn0 + n_off + ni * 16 + lrow;
#pragma unroll
      for (int p = 0; p < 4; ++p)
        C[(size_t)(row0 + p) * SS + col] = acc[mi][ni][p];
    }
}

__global__ __launch_bounds__(256)
void attn_softmax_rows(float* __restrict__ w) {
  float* p = w + (size_t)blockIdx.x * SS;
  const int t = threadIdx.x;
  float4* p4 = (float4*)p;
  float4 v0 = p4[t];
  float4 v1 = p4[t + 256];

  float m = fmaxf(fmaxf(fmaxf(v0.x, v0.y), fmaxf(v0.z, v0.w)),
                  fmaxf(fmaxf(v1.x, v1.y), fmaxf(v1.z, v1.w)));
#pragma unroll
  for (int off = 32; off >= 1; off >>= 1) m = fmaxf(m, __shfl_xor(m, off, 64));
  __shared__ float redm[4];
  __shared__ float reds[4];
  const int wv = t >> 6, lane = t & 63;
  if (lane == 0) redm[wv] = m;
  __syncthreads();
  m = fmaxf(fmaxf(redm[0], redm[1]), fmaxf(redm[2], redm[3]));

  v0.x = __expf(v0.x - m); v0.y = __expf(v0.y - m);
  v0.z = __expf(v0.z - m); v0.w = __expf(v0.w - m);
  v1.x = __expf(v1.x - m); v1.y = __expf(v1.y - m);
  v1.z = __expf(v1.z - m); v1.w = __expf(v1.w - m);

  float s = v0.x + v0.y + v0.z + v0.w + v1.x + v1.y + v1.z + v1.w;
#pragma unroll
  for (int off = 32; off >= 1; off >>= 1) s += __shfl_xor(s, off, 64);
  if (lane == 0) reds[wv] = s;
  __syncthreads();
  s = reds[0] + reds[1] + reds[2] + reds[3];

  const float inv = __fdividef(1.0f, s);
  v0.x *= inv; v0.y *= inv; v0.z *= inv; v0.w *= inv;
  v1.x *= inv; v1.y *= inv; v1.z *= inv; v1.w *= inv;
  p4[t] = v0;
  p4[t + 256] = v1;
}

__global__ __launch_bounds__(256, 1)
void attn_gemm2_ctx_f16(const float* __restrict__ w,
                        const float* __restrict__ src,
                        float* __restrict__ out) {
  const int b   = blockIdx.z;
  const int tm0 = blockIdx.y * 128;
  const int tn0 = blockIdx.x * 128;
  const float* A  = w + (size_t)b * TT * SS;
  const float* Bs = src + (size_t)b * SS * DD;
  float* C = out + (size_t)b * TT * DD;

  __shared__ __align__(16) _Float16 smA[128 * 32];
  __shared__ __align__(16) _Float16 smB[128 * 32];

  const int t     = threadIdx.x;
  const int lane  = t & 63;
  const int wv    = t >> 6;
  const int m_off = (wv & 1) * 64;
  const int n_off = (wv >> 1) * 64;
  const int q     = lane >> 4;
  const int lrow  = lane & 15;

  const int bn    = t & 127;
  const int bh2   = t >> 7;
  const int bs2   = (bn >> 1) & 3;
  const int slot0 = (2 * bh2) ^ bs2;
  const int slot1 = (2 * bh2 + 1) ^ bs2;

  f32x4 acc[4][4];
#pragma unroll
  for (int i = 0; i < 4; ++i)
#pragma unroll
    for (int j = 0; j < 4; ++j) acc[i][j] = (f32x4)0.0f;

  for (int kt = 0; kt < SS; kt += 32) {
    __syncthreads();
#pragma unroll
    for (int h = 0; h < 2; ++h) {
      const int c  = t + h * 256;
      const int r  = c >> 2;
      const int j  = c & 3;
      const int gk = j ^ ((r >> 1) & 3);
      const float* ga = A + (size_t)(tm0 + r) * SS + kt + gk * 8;
      float4 v0 = *(const float4*)ga;
      float4 v1 = *(const float4*)(ga + 4);
      f16x8 hv;
      hv[0] = (_Float16)v0.x; hv[1] = (_Float16)v0.y;
      hv[2] = (_Float16)v0.z; hv[3] = (_Float16)v0.w;
      hv[4] = (_Float16)v1.x; hv[5] = (_Float16)v1.y;
      hv[6] = (_Float16)v1.z; hv[7] = (_Float16)v1.w;
      *(f16x8*)(smA + c * 8) = hv;
    }
    {
      const float* gb = Bs + (size_t)(kt + bh2 * 16) * DD + (tn0 + bn);
      f16x8 c0, c1;
#pragma unroll
      for (int kk = 0; kk < 8; ++kk) c0[kk] = (_Float16)gb[(size_t)kk * DD];
#pragma unroll
      for (int kk = 0; kk < 8; ++kk) c1[kk] = (_Float16)gb[(size_t)(kk + 8) * DD];
      *(f16x8*)(smB + bn * 32 + slot0 * 8) = c0;
      *(f16x8*)(smB + bn * 32 + slot1 * 8) = c1;
    }
    __syncthreads();

    f16x8 af[4], bfr[4];
#pragma unroll
    for (int mi = 0; mi < 4; ++mi) {
      const int r   = m_off + mi * 16 + lrow;
      const int off = (r * 4 + (q ^ ((r >> 1) & 3))) * 8;
      af[mi] = *(const f16x8*)(smA + off);
    }
#pragma unroll
    for (int ni = 0; ni < 4; ++ni) {
      const int n   = n_off + ni * 16 + lrow;
      const int off = n * 32 + (q ^ ((n >> 1) & 3)) * 8;
      bfr[ni] = *(const f16x8*)(smB + off);
    }
#pragma unroll
    for (int mi = 0; mi < 4; ++mi)
#pragma unroll
      for (int ni = 0; ni < 4; ++ni)
        acc[mi][ni] = __builtin_amdgcn_mfma_f32_16x16x32_f16(af[mi], bfr[ni], acc[mi][ni], 0, 0, 0);
  }

#pragma unroll
  for (int mi = 0; mi < 4; ++mi)
#pragma unroll
    for (int ni = 0; ni < 4; ++ni) {
      const int row0 = tm0 + m_off + mi * 16 + q * 4;
      const int col  = tn0 + n_off + ni * 16 + lrow;
#pragma unroll
      for (int p = 0; p < 4; ++p)
        C[(size_t)(row0 + p) * DD + col] = acc[mi][ni][p];
    }
}

extern "C" void kernel_launch(void* const* d_in, const int* in_sizes, int n_in,
                              void* d_out, int out_size, void* d_ws, size_t ws_size,
                              hipStream_t stream) {
  const float* trg = (const float*)d_in[0];
  const float* src = (const float*)d_in[1];
  float* ctx = (float*)d_out;
  float* wts = (float*)d_out + (size_t)BB * TT * DD;

  const size_t NT = (size_t)BB * TT * DD;  // 16,777,216
  const size_t NW = (size_t)BB * TT * SS;  // 33,554,432
  const size_t need = (4 * NT + NW) * 2;   // 201,326,592 B = 192 MiB

  if (ws_size >= need) {
    _Float16* tH16 = (_Float16*)d_ws;
    _Float16* sH16 = tH16 + NT;
    _Float16* sL16 = sH16 + NT;
    _Float16* srcT = sL16 + NT;
    _Float16* w16  = srcT + NT;

    conv_trg_f16<<<dim3(NT / (8 * 256)), 256, 0, stream>>>(trg, tH16);
    conv_src_f16_hilo_t<<<dim3(DD / 64, SS / 64, BB), 256, 0, stream>>>(src, sH16, sL16, srcT);
    attn_gemm1_pipe<<<dim3(SS / 256, TT / 256, BB), 512, 0, stream>>>(tH16, sH16, sL16, wts);
    attn_softmax_w16<<<dim3(BB * TT), 64, 0, stream>>>(wts, w16);
    attn_gemm2_pipe<<<dim3(DD / 256, TT / 256, BB), 512, 0, stream>>>(w16, srcT, ctx);
  } else {
    attn_gemm1_scores_bf16x3<<<dim3(SS / 128, TT / 128, BB), 256, 0, stream>>>(trg, src, wts);
    attn_softmax_rows<<<dim3(BB * TT), 256, 0, stream>>>(wts);
    attn_gemm2_ctx_f16<<<dim3(DD / 128, TT / 128, BB), 256, 0, stream>>>(wts, src, ctx);
  }
}